// Round 4
// baseline (647.713 us; speedup 1.0000x reference)
//
#include <hip/hip_runtime.h>
#include <hip/hip_bf16.h>

// B=2, S=2048, HID=1024, NH=16, HD=64
#define B_    2
#define S_    2048
#define HID_  1024
#define NH_   16
#define HD_   64
#define M_    (B_ * S_)          // 4096 rows
#define NEGB_ (-1.0e30f)         // mask bias in log2 domain; exp2 -> 0
#define LOG2E 1.44269504088896340736f
#define X_ELEMS 4194304          // B*S*HID

typedef __bf16 bf16;
typedef bf16  bf16x8 __attribute__((ext_vector_type(8)));
typedef float f32x4  __attribute__((ext_vector_type(4)));

static __device__ __forceinline__ f32x4 mfma16(bf16x8 a, bf16x8 b, f32x4 c) {
    return __builtin_amdgcn_mfma_f32_16x16x32_bf16(a, b, c, 0, 0, 0);
}

// ---------------- prep kernels ----------------

__global__ void cast3(const float* __restrict__ a, const float* __restrict__ b,
                      const float* __restrict__ c, bf16* __restrict__ oa,
                      bf16* __restrict__ ob, bf16* __restrict__ oc) {
    const float* in = blockIdx.y == 0 ? a : blockIdx.y == 1 ? b : c;
    bf16* out = blockIdx.y == 0 ? oa : blockIdx.y == 1 ? ob : oc;
    int i = (blockIdx.x * 256 + threadIdx.x) * 4;
    float4 v = *(const float4*)(in + i);
    out[i + 0] = (bf16)v.x;
    out[i + 1] = (bf16)v.y;
    out[i + 2] = (bf16)v.z;
    out[i + 3] = (bf16)v.w;
}

// Wq_eff[h*64+j][i] = LOG2E * sum_d Ww[j][d] * Wq[h*64+d][i]; also bq_eff.
__global__ __launch_bounds__(256) void fuse_wq(const float* __restrict__ Ww,
                                               const float* __restrict__ Wq,
                                               const float* __restrict__ bq,
                                               const float* __restrict__ bw,
                                               bf16* __restrict__ Wq_eff,
                                               float* __restrict__ bq_eff) {
    __shared__ float ww[64][64];
    const int h = blockIdx.x >> 2, chunk = blockIdx.x & 3;
    const int i = chunk * 256 + threadIdx.x;
    for (int t = threadIdx.x; t < 4096; t += 256) ww[t >> 6][t & 63] = Ww[t];
    __syncthreads();
    float col[64];
    #pragma unroll
    for (int d = 0; d < 64; ++d) col[d] = Wq[(size_t)(h * 64 + d) * 1024 + i];
    for (int j = 0; j < 64; ++j) {
        float acc = 0.f;
        #pragma unroll
        for (int d = 0; d < 64; ++d) acc += ww[j][d] * col[d];
        Wq_eff[(size_t)(h * 64 + j) * 1024 + i] = (bf16)(acc * LOG2E);
    }
    if (chunk == 0 && threadIdx.x < 64) {
        int j = threadIdx.x;
        float acc = bw[j];
        for (int d = 0; d < 64; ++d) acc += ww[j][d] * bq[h * 64 + d];
        bq_eff[h * 64 + j] = acc * LOG2E;
    }
}

// ---------------- Q/K projections (grid.z = 0,1), BM=128 BN=128 ----------------
__global__ __launch_bounds__(256) void projQK(const float* __restrict__ Aq,
                                              const float* __restrict__ Ak,
                                              const bf16* __restrict__ W0,
                                              const bf16* __restrict__ W1,
                                              const float* __restrict__ b0,
                                              const float* __restrict__ b1,
                                              bf16* __restrict__ Qw,
                                              bf16* __restrict__ Kh) {
    const int z = blockIdx.z;
    const float* A = z == 0 ? Aq : Ak;
    const bf16* W = z == 0 ? W0 : W1;
    const float* bias = z == 0 ? b0 : b1;
    bf16* out = z == 0 ? Qw : Kh;

    const int wave = threadIdx.x >> 6, lane = threadIdx.x & 63;
    const int lr = lane & 15, kg = lane >> 4;
    const int m_base = blockIdx.x * 128 + wave * 16;
    const int n0 = blockIdx.y * 128;

    f32x4 acc[2][8] = {};
    for (int k0 = 0; k0 < HID_; k0 += 32) {
        bf16x8 af[2];
        #pragma unroll
        for (int t = 0; t < 2; ++t) {
            const float4* ap = (const float4*)(A + (size_t)(m_base + t * 64 + lr) * HID_ + k0 + kg * 8);
            float4 x0 = ap[0], x1 = ap[1];
            af[t][0] = (bf16)x0.x; af[t][1] = (bf16)x0.y; af[t][2] = (bf16)x0.z; af[t][3] = (bf16)x0.w;
            af[t][4] = (bf16)x1.x; af[t][5] = (bf16)x1.y; af[t][6] = (bf16)x1.z; af[t][7] = (bf16)x1.w;
        }
        #pragma unroll
        for (int cg = 0; cg < 8; ++cg) {
            int col = n0 + cg * 16 + lr;
            bf16x8 bfr = *(const bf16x8*)(W + (size_t)col * HID_ + k0 + kg * 8);
            acc[0][cg] = mfma16(af[0], bfr, acc[0][cg]);
            acc[1][cg] = mfma16(af[1], bfr, acc[1][cg]);
        }
    }
    #pragma unroll
    for (int t = 0; t < 2; ++t) {
        #pragma unroll
        for (int cg = 0; cg < 8; ++cg) {
            int col = n0 + cg * 16 + lr;
            float bv = bias[col];
            int h = col >> 6, d = col & 63;
            #pragma unroll
            for (int r = 0; r < 4; ++r) {
                int m = m_base + t * 64 + kg * 4 + r;
                int b = m >> 11, s = m & 2047;
                out[((size_t)(b * NH_ + h) * S_ + s) * HD_ + d] = (bf16)(acc[t][cg][r] + bv);
            }
        }
    }
}

// ---------------- V projection, BM=128 BN=64, LDS-transposed stores ----------------
__global__ __launch_bounds__(256) void projV(const float* __restrict__ A,
                                             const bf16* __restrict__ W,
                                             const float* __restrict__ bias,
                                             bf16* __restrict__ Vt) {
    __shared__ bf16 vt[64][136];   // [d][s_local], stride 136 elems = 272B (16B-aligned rows)
    const int wave = threadIdx.x >> 6, lane = threadIdx.x & 63;
    const int lr = lane & 15, kg = lane >> 4;
    const int m_base = blockIdx.x * 128 + wave * 16;
    const int n0 = blockIdx.y * 64;
    const int b = (blockIdx.x * 128) >> 11, s_base = (blockIdx.x * 128) & 2047;
    const int h = n0 >> 6;

    f32x4 acc[2][4] = {};
    for (int k0 = 0; k0 < HID_; k0 += 32) {
        bf16x8 af[2];
        #pragma unroll
        for (int t = 0; t < 2; ++t) {
            const float4* ap = (const float4*)(A + (size_t)(m_base + t * 64 + lr) * HID_ + k0 + kg * 8);
            float4 x0 = ap[0], x1 = ap[1];
            af[t][0] = (bf16)x0.x; af[t][1] = (bf16)x0.y; af[t][2] = (bf16)x0.z; af[t][3] = (bf16)x0.w;
            af[t][4] = (bf16)x1.x; af[t][5] = (bf16)x1.y; af[t][6] = (bf16)x1.z; af[t][7] = (bf16)x1.w;
        }
        #pragma unroll
        for (int cg = 0; cg < 4; ++cg) {
            int col = n0 + cg * 16 + lr;
            bf16x8 bfr = *(const bf16x8*)(W + (size_t)col * HID_ + k0 + kg * 8);
            acc[0][cg] = mfma16(af[0], bfr, acc[0][cg]);
            acc[1][cg] = mfma16(af[1], bfr, acc[1][cg]);
        }
    }
    const int wlocal = wave * 16;   // this wave's 16-row s chunk base (t adds 64)
    #pragma unroll
    for (int t = 0; t < 2; ++t)
        #pragma unroll
        for (int cg = 0; cg < 4; ++cg) {
            float bv = bias[n0 + cg * 16 + lr];
            #pragma unroll
            for (int r = 0; r < 4; ++r)
                vt[cg * 16 + lr][t * 64 + wlocal + kg * 4 + r] = (bf16)(acc[t][cg][r] + bv);
        }
    __syncthreads();
    // cooperative coalesced store: 64 d-rows x 128 s (256B per row)
    const int d = threadIdx.x >> 2, c = threadIdx.x & 3;
    bf16* dst = Vt + ((size_t)(b * NH_ + h) * HD_ + d) * S_ + s_base;
    #pragma unroll
    for (int k = 0; k < 4; ++k) {
        int i = c + 4 * k;            // consecutive c -> contiguous 16B chunks
        *(bf16x8*)(dst + i * 8) = *(const bf16x8*)&vt[d][i * 8];
    }
}

// ---------------- fused attention ----------------
// 512 threads / 8 waves: wave = (hf, g). No inline waits: compiler handles
// LDS ordering with counted lgkmcnt and pipelines V/K loads across it.
__global__ __launch_bounds__(512) void attn_kernel(const bf16* __restrict__ Qw,
                                                   const bf16* __restrict__ Kh,
                                                   const bf16* __restrict__ Vt,
                                                   const int* __restrict__ mask,
                                                   float* __restrict__ attn_out,
                                                   bf16* __restrict__ Xh) {
    __shared__ bf16 negb[S_];                       // 4 KB mask bias (0 / -1e30)
    __shared__ float lsum[2][4][16];                // row-sum exchange
    __shared__ __align__(16) float sbuf[8][16][68]; // 34.8 KB per-wave P tiles

    const int wave = threadIdx.x >> 6, lane = threadIdx.x & 63;
    const int lr = lane & 15, kg = lane >> 4;
    const int g = wave & 3, hf = wave >> 2;

    const int wg = blockIdx.x;                      // 1024 blocks, 8-XCD bijective swizzle
    const int flat = (wg & 7) * 128 + (wg >> 3);
    const int qtile = flat & 31;
    const int bh = flat >> 5;
    const int b = bh >> 4, h = bh & 15;
    const int q0 = qtile * 64 + g * 16;

    const bf16* Qh = Qw + (size_t)bh * S_ * HD_;
    const bf16* Kb = Kh + (size_t)bh * S_ * HD_;
    const bf16* Vb = Vt + (size_t)bh * HD_ * S_;
    const int*  mb = mask + b * S_;
    float* arow = attn_out + (size_t)bh * S_ * S_;
    float* sb = &sbuf[wave][0][0];                  // [16][68]

    for (int t = threadIdx.x; t < S_; t += 512)
        negb[t] = (bf16)(mb[t] ? 0.f : NEGB_);
    __syncthreads();

    bf16x8 a0 = *(const bf16x8*)(Qh + (size_t)(q0 + lr) * HD_ + kg * 8);
    bf16x8 a1 = *(const bf16x8*)(Qh + (size_t)(q0 + lr) * HD_ + 32 + kg * 8);

    auto energy = [&](int kv0, f32x4* e) {
        #pragma unroll
        for (int cg = 0; cg < 4; ++cg) {
            int kv = kv0 + cg * 16 + lr;
            bf16x8 k0 = *(const bf16x8*)(Kb + (size_t)kv * HD_ + kg * 8);
            bf16x8 k1 = *(const bf16x8*)(Kb + (size_t)kv * HD_ + 32 + kg * 8);
            f32x4 z = {};
            z = mfma16(a0, k0, z);
            z = mfma16(a1, k1, z);
            float nb = (float)negb[kv];
            z[0] += nb; z[1] += nb; z[2] += nb; z[3] += nb;
            e[cg] = z;
        }
    };

    // ---- pass 1: per-lane partial row sums of exp2(e) ----
    float psum[4] = {0.f, 0.f, 0.f, 0.f};
    for (int t = 0; t < 16; ++t) {
        f32x4 e[4];
        energy(hf * 64 + t * 128, e);
        #pragma unroll
        for (int r = 0; r < 4; ++r)
            psum[r] += exp2f(e[0][r]) + exp2f(e[1][r]) +
                       exp2f(e[2][r]) + exp2f(e[3][r]);
    }
    #pragma unroll
    for (int r = 0; r < 4; ++r) {
        float s = psum[r];
        s += __shfl_xor(s, 1);
        s += __shfl_xor(s, 2);
        s += __shfl_xor(s, 4);
        s += __shfl_xor(s, 8);
        psum[r] = s;
    }
    if (lr == 0) {
        #pragma unroll
        for (int r = 0; r < 4; ++r) lsum[hf][g][kg * 4 + r] = psum[r];
    }
    __syncthreads();
    float lg2l[4];
    #pragma unroll
    for (int r = 0; r < 4; ++r)
        lg2l[r] = __log2f(lsum[0][g][kg * 4 + r] + lsum[1][g][kg * 4 + r]);

    // ---- pass 2: P -> LDS stage -> PV MFMA + coalesced f32x4 stores ----
    f32x4 X[4] = {};
    for (int t = 0; t < 16; ++t) {
        const int kv0 = hf * 64 + t * 128;
        f32x4 e[4];
        energy(kv0, e);
        #pragma unroll
        for (int cg = 0; cg < 4; ++cg) {
            #pragma unroll
            for (int r = 0; r < 4; ++r)
                sb[(kg * 4 + r) * 68 + cg * 16 + lr] = exp2f(e[cg][r] - lg2l[r]);
        }
        // PV A-fragments (f32 -> bf16)
        f32x4 p0a = *(const f32x4*)&sb[lr * 68 + kg * 8];
        f32x4 p0b = *(const f32x4*)&sb[lr * 68 + kg * 8 + 4];
        f32x4 p1a = *(const f32x4*)&sb[lr * 68 + 32 + kg * 8];
        f32x4 p1b = *(const f32x4*)&sb[lr * 68 + 32 + kg * 8 + 4];
        bf16x8 pa0, pa1;
        #pragma unroll
        for (int j = 0; j < 4; ++j) {
            pa0[j] = (bf16)p0a[j]; pa0[4 + j] = (bf16)p0b[j];
            pa1[j] = (bf16)p1a[j]; pa1[4 + j] = (bf16)p1b[j];
        }
        #pragma unroll
        for (int dg = 0; dg < 4; ++dg) {
            bf16x8 v0 = *(const bf16x8*)(Vb + (size_t)(dg * 16 + lr) * S_ + kv0 + kg * 8);
            bf16x8 v1 = *(const bf16x8*)(Vb + (size_t)(dg * 16 + lr) * S_ + kv0 + 32 + kg * 8);
            X[dg] = mfma16(pa0, v0, X[dg]);
            X[dg] = mfma16(pa1, v1, X[dg]);
        }
        // coalesced attention stores: 4 rows x 256B per instruction
        #pragma unroll
        for (int it = 0; it < 4; ++it) {
            int row = it * 4 + kg;
            f32x4 vst = *(const f32x4*)&sb[row * 68 + lr * 4];
            *(f32x4*)(arow + (size_t)(q0 + row) * S_ + kv0 + lr * 4) = vst;
        }
    }

    // ---- merge X across hf halves (xb aliases sbuf region) ----
    __syncthreads();
    float* xb = (float*)sbuf;   // [4][16][68]
    if (hf == 1) {
        #pragma unroll
        for (int dg = 0; dg < 4; ++dg)
            #pragma unroll
            for (int r = 0; r < 4; ++r)
                xb[(g * 16 + kg * 4 + r) * 68 + dg * 16 + lr] = X[dg][r];
    }
    __syncthreads();
    if (hf == 0) {
        #pragma unroll
        for (int dg = 0; dg < 4; ++dg) {
            #pragma unroll
            for (int r = 0; r < 4; ++r) {
                int q = q0 + kg * 4 + r;
                float v = X[dg][r] + xb[(g * 16 + kg * 4 + r) * 68 + dg * 16 + lr];
                Xh[((size_t)(b * S_ + q)) * HID_ + h * HD_ + dg * 16 + lr] = (bf16)v;
            }
        }
    }
}

// ---------------- output projection: out = X @ Wo^T + bo, BM=128 BN=128 ----------------
__global__ __launch_bounds__(256) void out_gemm(const bf16* __restrict__ X,
                                                const bf16* __restrict__ Wo,
                                                const float* __restrict__ bo,
                                                float* __restrict__ out) {
    const int wave = threadIdx.x >> 6, lane = threadIdx.x & 63;
    const int lr = lane & 15, kg = lane >> 4;
    const int m_base = blockIdx.x * 128 + wave * 16;
    const int n0 = blockIdx.y * 128;

    f32x4 acc[2][8] = {};
    for (int k0 = 0; k0 < HID_; k0 += 32) {
        bf16x8 af0 = *(const bf16x8*)(X + (size_t)(m_base + lr) * HID_ + k0 + kg * 8);
        bf16x8 af1 = *(const bf16x8*)(X + (size_t)(m_base + 64 + lr) * HID_ + k0 + kg * 8);
        #pragma unroll
        for (int cg = 0; cg < 8; ++cg) {
            int col = n0 + cg * 16 + lr;
            bf16x8 bfr = *(const bf16x8*)(Wo + (size_t)col * HID_ + k0 + kg * 8);
            acc[0][cg] = mfma16(af0, bfr, acc[0][cg]);
            acc[1][cg] = mfma16(af1, bfr, acc[1][cg]);
        }
    }
    #pragma unroll
    for (int t = 0; t < 2; ++t) {
        #pragma unroll
        for (int cg = 0; cg < 8; ++cg) {
            int col = n0 + cg * 16 + lr;
            float bv = bo[col];
            #pragma unroll
            for (int r = 0; r < 4; ++r)
                out[(size_t)(m_base + t * 64 + kg * 4 + r) * HID_ + col] = acc[t][cg][r] + bv;
        }
    }
}

// ---------------- launch ----------------
extern "C" void kernel_launch(void* const* d_in, const int* in_sizes, int n_in,
                              void* d_out, int out_size, void* d_ws, size_t ws_size,
                              hipStream_t stream) {
    const float* query = (const float*)d_in[0];
    const float* key_  = (const float*)d_in[1];
    const float* value = (const float*)d_in[2];
    const int*   mask  = (const int*)d_in[3];
    const float* Wq = (const float*)d_in[4];
    const float* bq = (const float*)d_in[5];
    const float* Wk = (const float*)d_in[6];
    const float* bk = (const float*)d_in[7];
    const float* Wv = (const float*)d_in[8];
    const float* bv = (const float*)d_in[9];
    const float* Ww = (const float*)d_in[10];
    const float* bw = (const float*)d_in[11];
    const float* Wo = (const float*)d_in[12];
    const float* bo = (const float*)d_in[13];
    float* out = (float*)d_out;

    char* ws = (char*)d_ws;
    size_t off = 0;
    auto alloc = [&](size_t bytes) {
        void* p = ws + off;
        off += (bytes + 255) & ~(size_t)255;
        return p;
    };
    bf16*  Wq_eff = (bf16*)alloc((size_t)HID_ * HID_ * 2);
    float* bq_eff = (float*)alloc((size_t)HID_ * 4);
    bf16*  Wk_b   = (bf16*)alloc((size_t)HID_ * HID_ * 2);
    bf16*  Wv_b   = (bf16*)alloc((size_t)HID_ * HID_ * 2);
    bf16*  Wo_b   = (bf16*)alloc((size_t)HID_ * HID_ * 2);
    bf16*  Qw     = (bf16*)alloc((size_t)M_ * HID_ * 2);   // [B][H][S][D], pre-scaled log2e
    bf16*  Kh     = (bf16*)alloc((size_t)M_ * HID_ * 2);   // [B][H][S][D]
    bf16*  Vt     = (bf16*)alloc((size_t)M_ * HID_ * 2);   // [B][H][D][S]
    bf16*  Xh     = (bf16*)alloc((size_t)M_ * HID_ * 2);   // [B][S][HID]
    (void)ws_size; (void)in_sizes; (void)n_in; (void)out_size;

    dim3 gcast(1024, 3);
    cast3<<<gcast, 256, 0, stream>>>(Wk, Wv, Wo, Wk_b, Wv_b, Wo_b);
    fuse_wq<<<64, 256, 0, stream>>>(Ww, Wq, bq, bw, Wq_eff, bq_eff);

    dim3 gqk(M_ / 128, HID_ / 128, 2);   // (32,8,2)
    projQK<<<gqk, 256, 0, stream>>>(query, key_, Wq_eff, Wk_b, bq_eff, bk, Qw, Kh);
    dim3 gv(M_ / 128, HID_ / 64);        // (32,16)
    projV<<<gv, 256, 0, stream>>>(value, Wv_b, bv, Vt);

    attn_kernel<<<1024, 512, 0, stream>>>(Qw, Kh, Vt, mask, out + X_ELEMS, Xh);

    dim3 gout(M_ / 128, HID_ / 128);     // (32,8)
    out_gemm<<<gout, 256, 0, stream>>>(Xh, Wo_b, bo, out);
}